// Round 4
// baseline (129.412 us; speedup 1.0000x reference)
//
#include <hip/hip_runtime.h>

#define NPTS 96
#define HID  64
#define RANK 32

typedef float f2 __attribute__((ext_vector_type(2)));
typedef float f4 __attribute__((ext_vector_type(4)));

// ws layout (floats):
//   plain[axis][f][n] : axis*RANK*NPTS + f*NPTS + n
//   trans[axis][n][f] : TRANS_OFF + (axis*NPTS+n)*RANK + f
#define TRANS_OFF (4 * RANK * NPTS)

// -------- Kernel 1: the 4 tiny MLPs -> factor matrices in ws --------
__global__ __launch_bounds__(64) void spinn_mlp(
    const float* __restrict__ t, const float* __restrict__ x,
    const float* __restrict__ y, const float* __restrict__ z,
    const float* __restrict__ W1, const float* __restrict__ b1,
    const float* __restrict__ W2, const float* __restrict__ b2,
    const float* __restrict__ W3, const float* __restrict__ b3,
    float* __restrict__ ws)
{
    const int n    = blockIdx.x;   // point 0..95
    const int axis = blockIdx.y;   // 0..3
    const int j    = threadIdx.x;  // 0..63

    const float* coords[4] = { t, x, y, z };
    const float c = coords[axis][n];

    __shared__ float h1[HID];
    __shared__ float h2[HID];

    h1[j] = tanhf(fmaf(c, W1[axis * HID + j], b1[axis * HID + j]));
    __syncthreads();

    float a = b2[axis * HID + j];
    #pragma unroll
    for (int k = 0; k < HID; ++k)
        a = fmaf(h1[k], W2[(axis * HID + k) * HID + j], a);
    h2[j] = tanhf(a);
    __syncthreads();

    if (j < RANK) {
        float o = b3[axis * RANK + j];
        #pragma unroll
        for (int k = 0; k < HID; ++k)
            o = fmaf(h2[k], W3[(axis * HID + k) * RANK + j], o);
        ws[axis * RANK * NPTS + j * NPTS + n]        = o; // plain [axis][f][n]
        ws[TRANS_OFF + (axis * NPTS + n) * RANK + j] = o; // trans [axis][n][f]
    }
}

// -------- Kernel 2: rank-32 CP reconstruction, 96^4 fp32 output --------
// f-pair packing: q2[k][z] = (g[2k]*fz[2k][z0+z], g[2k+1]*fz[2k+1][z0+z]),
// one v_pk_fma_f32 per (f-pair, z) with the raw (fx[2k],fx[2k+1]) pair —
// no scalar broadcast needed; result = horizontal sum of the 2 lanes.
__global__ __launch_bounds__(192) void spinn_outer(
    const float* __restrict__ ws, float* __restrict__ out)
{
    const int tt  = blockIdx.x;        // t: 0..95
    const int yb  = blockIdx.y;        // y block: 0..11
    const int xh  = blockIdx.z;        // x half: 0..1
    const int tid = threadIdx.x;       // 0..191
    const int yq  = tid / 24;          // 0..7
    const int z4  = tid % 24;          // 0..23
    const int yy  = yb * 8 + yq;
    const int z0  = z4 * 4;

    const float* ftT = ws + TRANS_OFF + (0 * NPTS + tt) * RANK;
    const float* fyT = ws + TRANS_OFF + (2 * NPTS + yy) * RANK;
    const float* fzP = ws + 3 * RANK * NPTS;   // fz[f][n]

    // q2: 16 f-pairs x 4 z, register-resident (128 VGPRs)
    f2 q2[16][4];
    #pragma unroll
    for (int k = 0; k < 16; ++k) {
        const float g0 = ftT[2 * k]     * fyT[2 * k];
        const float g1 = ftT[2 * k + 1] * fyT[2 * k + 1];
        #pragma unroll
        for (int zz = 0; zz < 4; ++zz) {
            q2[k][zz] = f2{ g0 * fzP[(2 * k) * NPTS + z0 + zz],
                            g1 * fzP[(2 * k + 1) * NPTS + z0 + zz] };
        }
    }

    const int x0 = xh * 48;
    // Launder the fx base pointer into VGPRs so the (block-uniform) loads take
    // the in-order-vmcnt VMEM path and get pipelined by the compiler.
    const float* fxl = ws + TRANS_OFF + (size_t)(1 * NPTS) * RANK + (size_t)x0 * RANK;
    asm("" : "+v"(fxl));

    float* outp = out + (size_t)tt * NPTS * NPTS * NPTS
                      + (size_t)x0 * NPTS * NPTS
                      + (size_t)yy * NPTS + z0;
    float* stp = outp;

    f4 pend;

    #pragma unroll 1
    for (int xs = 0; xs < 48; ++xs) {
        // 8 x 16B loads of fx[32] for this x (all lanes same addr -> L1 broadcast)
        const f4* fv = (const f4*)(fxl + (size_t)xs * RANK);
        f4 Ld[8];
        #pragma unroll
        for (int j = 0; j < 8; ++j) Ld[j] = fv[j];

        // Keep program order loads -> store so the pre-compute wait is vmcnt(1),
        // never a full store drain.
        __builtin_amdgcn_sched_barrier(0);

        if (xs) {  // store previous iteration's result (1-deep store delay)
            __builtin_nontemporal_store(pend, (f4*)stp);
            stp += NPTS * NPTS;
        }

        f2 acc[8];
        #pragma unroll
        for (int c = 0; c < 8; ++c) acc[c] = f2{0.f, 0.f};

        // k even -> chains 0..3, k odd -> chains 4..7 (8 independent chains)
        #define DO_K(Lj, lohi, kk)                                              \
        {                                                                       \
            f2 p_ = __builtin_shufflevector((Lj), (Lj), 2*(lohi), 2*(lohi)+1);  \
            asm("v_pk_fma_f32 %0, %2, %3, %0\n\t"                               \
                "v_pk_fma_f32 %1, %2, %4, %1"                                   \
                : "+v"(acc[(((kk)&1)<<2)+0]), "+v"(acc[(((kk)&1)<<2)+1])        \
                : "v"(p_), "v"(q2[kk][0]), "v"(q2[kk][1]));                     \
            asm("v_pk_fma_f32 %0, %2, %3, %0\n\t"                               \
                "v_pk_fma_f32 %1, %2, %4, %1"                                   \
                : "+v"(acc[(((kk)&1)<<2)+2]), "+v"(acc[(((kk)&1)<<2)+3])        \
                : "v"(p_), "v"(q2[kk][2]), "v"(q2[kk][3]));                     \
        }

        DO_K(Ld[0], 0, 0)   DO_K(Ld[0], 1, 1)
        DO_K(Ld[1], 0, 2)   DO_K(Ld[1], 1, 3)
        DO_K(Ld[2], 0, 4)   DO_K(Ld[2], 1, 5)
        DO_K(Ld[3], 0, 6)   DO_K(Ld[3], 1, 7)
        DO_K(Ld[4], 0, 8)   DO_K(Ld[4], 1, 9)
        DO_K(Ld[5], 0, 10)  DO_K(Ld[5], 1, 11)
        DO_K(Ld[6], 0, 12)  DO_K(Ld[6], 1, 13)
        DO_K(Ld[7], 0, 14)  DO_K(Ld[7], 1, 15)
        #undef DO_K

        // horizontal sum: out_z = sum over both pack lanes, both chains
        pend = f4{ (acc[0].x + acc[0].y) + (acc[4].x + acc[4].y),
                   (acc[1].x + acc[1].y) + (acc[5].x + acc[5].y),
                   (acc[2].x + acc[2].y) + (acc[6].x + acc[6].y),
                   (acc[3].x + acc[3].y) + (acc[7].x + acc[7].y) };
    }
    __builtin_nontemporal_store(pend, (f4*)stp);
}

extern "C" void kernel_launch(void* const* d_in, const int* in_sizes, int n_in,
                              void* d_out, int out_size, void* d_ws, size_t ws_size,
                              hipStream_t stream)
{
    const float* t  = (const float*)d_in[0];
    const float* x  = (const float*)d_in[1];
    const float* y  = (const float*)d_in[2];
    const float* z  = (const float*)d_in[3];
    const float* W1 = (const float*)d_in[4];
    const float* b1 = (const float*)d_in[5];
    const float* W2 = (const float*)d_in[6];
    const float* b2 = (const float*)d_in[7];
    const float* W3 = (const float*)d_in[8];
    const float* b3 = (const float*)d_in[9];

    float* ws  = (float*)d_ws;
    float* out = (float*)d_out;

    spinn_mlp<<<dim3(NPTS, 4), 64, 0, stream>>>(t, x, y, z, W1, b1, W2, b2, W3, b3, ws);
    spinn_outer<<<dim3(NPTS, 12, 2), 192, 0, stream>>>(ws, out);
}

// Round 6
// 85.549 us; speedup vs baseline: 1.5127x; 1.5127x over previous
//
#include <hip/hip_runtime.h>

#define NPTS 96
#define HID  64
#define RANK 32

typedef float f2 __attribute__((ext_vector_type(2)));

// ws layout (floats):
//   plain[axis][f][n] : axis*RANK*NPTS + f*NPTS + n
//   trans[axis][n][f] : TRANS_OFF + (axis*NPTS+n)*RANK + f
#define TRANS_OFF (4 * RANK * NPTS)

// -------- Kernel 1: the 4 tiny MLPs -> factor matrices in ws --------
__global__ __launch_bounds__(64) void spinn_mlp(
    const float* __restrict__ t, const float* __restrict__ x,
    const float* __restrict__ y, const float* __restrict__ z,
    const float* __restrict__ W1, const float* __restrict__ b1,
    const float* __restrict__ W2, const float* __restrict__ b2,
    const float* __restrict__ W3, const float* __restrict__ b3,
    float* __restrict__ ws)
{
    const int n    = blockIdx.x;   // point 0..95
    const int axis = blockIdx.y;   // 0..3
    const int j    = threadIdx.x;  // 0..63

    const float* coords[4] = { t, x, y, z };
    const float c = coords[axis][n];

    __shared__ float h1[HID];
    __shared__ float h2[HID];

    h1[j] = tanhf(fmaf(c, W1[axis * HID + j], b1[axis * HID + j]));
    __syncthreads();

    float a = b2[axis * HID + j];
    #pragma unroll
    for (int k = 0; k < HID; ++k)
        a = fmaf(h1[k], W2[(axis * HID + k) * HID + j], a);
    h2[j] = tanhf(a);
    __syncthreads();

    if (j < RANK) {
        float o = b3[axis * RANK + j];
        #pragma unroll
        for (int k = 0; k < HID; ++k)
            o = fmaf(h2[k], W3[(axis * HID + k) * RANK + j], o);
        ws[axis * RANK * NPTS + j * NPTS + n]        = o; // plain [axis][f][n]
        ws[TRANS_OFF + (axis * NPTS + n) * RANK + j] = o; // trans [axis][n][f]
    }
}

// -------- Kernel 2: rank-32 CP reconstruction, 96^4 fp32 output --------
// Thread owns (y, 2 consecutive z). f-pair packing:
//   q2[k][zz] = ( g[2k]*fz[2k][z0+zz], g[2k+1]*fz[2k+1][z0+zz] ),  g = ft*fy
// Inner loop per x: acc[zz] += (fx[2k],fx[2k+1]) * q2[k][zz]  (pk-fma, no
// broadcast needed); out = horizontal sum of the pair. ~100 VGPR ->
// launch_bounds(192,4) keeps VGPR<=128 i.e. 4 waves/SIMD for latency hiding.
__global__ __launch_bounds__(192, 4) void spinn_outer(
    const float* __restrict__ ws, float* __restrict__ out)
{
    const int tt  = blockIdx.x;        // t: 0..95
    const int yb  = blockIdx.y;        // y block: 0..23 (4 y each)
    const int xh  = blockIdx.z;        // x quarter: 0..3 (24 x each)
    const int tid = threadIdx.x;       // 0..191
    const int zp  = tid % 48;          // z pair index
    const int yq  = tid / 48;          // 0..3
    const int yy  = yb * 4 + yq;
    const int z0  = zp * 2;

    const float* ftT = ws + TRANS_OFF + (0 * NPTS + tt) * RANK;
    const float* fyT = ws + TRANS_OFF + (2 * NPTS + yy) * RANK;
    const float* fzP = ws + 3 * RANK * NPTS;   // fz[f][n]

    // q2: 16 f-pairs x 2 z = 64 VGPRs
    f2 q2[16][2];
    #pragma unroll
    for (int k = 0; k < 16; ++k) {
        const f2 ft2 = *(const f2*)(ftT + 2 * k);
        const f2 fy2 = *(const f2*)(fyT + 2 * k);
        const float g0 = ft2.x * fy2.x;
        const float g1 = ft2.y * fy2.y;
        const f2 za = *(const f2*)(fzP + (2 * k) * NPTS + z0);     // fz[2k][z0,z0+1]
        const f2 zb = *(const f2*)(fzP + (2 * k + 1) * NPTS + z0); // fz[2k+1][..]
        q2[k][0] = f2{ g0 * za.x, g1 * zb.x };
        q2[k][1] = f2{ g0 * za.y, g1 * zb.y };
    }

    const int x0 = xh * 24;
    const float* fxT = ws + TRANS_OFF + (1 * NPTS) * RANK;  // [x][f], uniform
    float* outp = out + (size_t)tt * NPTS * NPTS * NPTS
                      + (size_t)x0 * NPTS * NPTS
                      + (size_t)yy * NPTS + z0;

    #pragma unroll 2
    for (int xs = 0; xs < 24; ++xs) {
        const f2* fp = (const f2*)(fxT + (size_t)(x0 + xs) * RANK);  // uniform addr
        f2 a0 = { 0.f, 0.f }, a1 = { 0.f, 0.f };
        #pragma unroll
        for (int k = 0; k < 16; ++k) {
            const f2 p = fp[k];                       // (fx[2k], fx[2k+1])
            a0 = __builtin_elementwise_fma(p, q2[k][0], a0);
            a1 = __builtin_elementwise_fma(p, q2[k][1], a1);
        }
        const f2 r = { a0.x + a0.y, a1.x + a1.y };
        __builtin_nontemporal_store(r, (f2*)outp);
        outp += NPTS * NPTS;
    }
}

extern "C" void kernel_launch(void* const* d_in, const int* in_sizes, int n_in,
                              void* d_out, int out_size, void* d_ws, size_t ws_size,
                              hipStream_t stream)
{
    const float* t  = (const float*)d_in[0];
    const float* x  = (const float*)d_in[1];
    const float* y  = (const float*)d_in[2];
    const float* z  = (const float*)d_in[3];
    const float* W1 = (const float*)d_in[4];
    const float* b1 = (const float*)d_in[5];
    const float* W2 = (const float*)d_in[6];
    const float* b2 = (const float*)d_in[7];
    const float* W3 = (const float*)d_in[8];
    const float* b3 = (const float*)d_in[9];

    float* ws  = (float*)d_ws;
    float* out = (float*)d_out;

    spinn_mlp<<<dim3(NPTS, 4), 64, 0, stream>>>(t, x, y, z, W1, b1, W2, b2, W3, b3, ws);
    spinn_outer<<<dim3(NPTS, 24, 4), 192, 0, stream>>>(ws, out);
}